// Round 12
// baseline (367.749 us; speedup 1.0000x reference)
//
#include <hip/hip_runtime.h>
#include <hip/hip_bf16.h>

// Sizes (compile-time)
#define B_ 16
#define N_ 1024
#define CIN 24
#define EMB_ 64
#define HID_ 32
#define OUT_ 12
#define BH_ 32            // B*HEADS
#define RSQRT12 0.28867513459481287f
#define L2E 1.4426950408889634f
#define SCL (RSQRT12 * L2E)   // folded into q2 at write time

typedef unsigned uvec2 __attribute__((ext_vector_type(2)));
typedef float f2 __attribute__((ext_vector_type(2)));

// ---------------- workspace layout (floats) ----------------
#define OFF_Q2     0              // 393216  q node-major [node][bh][12], prescaled by SCL (reused as t1o)
#define OFF_K1     393216         // 393216  k bh-major   [bh][node][12] (reused as t1i)
#define OFF_K2     786432         // 393216  k node-major [node][bh][12]
#define OFF_ZI     1212416        // 32768   zinv2 [node][bh]
#define OFF_DEG    1245184        // 2048
#define OFF_INT    1247232        // int area (rp/cp/eids) ~24K ints
#define OFF_TEMP   1271296        // 1048576
#define OFF_WFT    2319872        // 12288
#define OFF_BF     2332160        // 128
#define OFF_XP     2332288        // 1572864
#define OFF_XT     3905152        // 393216  x node-major [node][b][c]

// ---------------- fused: qk projection (blocks 1..384) + graph prep/wfold (block 0) ----------------
__global__ __launch_bounds__(1024) void qk_prep_kernel(
    const float* __restrict__ x, const float* __restrict__ Wq, const float* __restrict__ bq,
    const float* __restrict__ Wk, const float* __restrict__ bk,
    float* __restrict__ q2, float* __restrict__ k1, float* __restrict__ k2,
    float* __restrict__ xT,
    const int* __restrict__ ei, int E,
    float* __restrict__ deg, int* __restrict__ rp, int* __restrict__ cp,
    int* __restrict__ eids,
    const float* __restrict__ We, const float* __restrict__ be,
    const float* __restrict__ Wih, const float* __restrict__ bih,
    float* __restrict__ WfT, float* __restrict__ bf) {
  __shared__ int cntL[1024];
  __shared__ int sL[1024];
  __shared__ int offL[1024];
  int tid = threadIdx.x;
  if (blockIdx.x == 0) {
    deg[tid] = 0.f; deg[N_ + tid] = 0.f;
    cntL[tid] = 0;
    { int lo = 0, hi2 = E;
      while (lo < hi2) { int mid = (lo + hi2) >> 1; if (ei[mid] < tid) lo = mid + 1; else hi2 = mid; }
      rp[tid] = lo; }
    if (tid == 0) rp[N_] = E;
    __syncthreads();
    for (int e = tid; e < E; e += 1024) atomicAdd(&cntL[ei[E + e]], 1);
    __syncthreads();
    int my = cntL[tid];
    sL[tid] = my;
    __syncthreads();
    for (int d = 1; d < 1024; d <<= 1) {
      int v = (tid >= d) ? sL[tid - d] : 0;
      __syncthreads();
      sL[tid] += v;
      __syncthreads();
    }
    int excl = sL[tid] - my;
    cp[tid] = excl;
    offL[tid] = excl;
    if (tid == 1023) cp[1024] = sL[tid];
    __syncthreads();
    for (int e = tid; e < E; e += 1024) {
      int p = atomicAdd(&offL[ei[E + e]], 1);
      eids[p] = e;
    }
    for (int i = tid; i < 128 * 96; i += 1024) {
      int o = i % 96, c = i / 96;
      float acc = 0.f;
#pragma unroll
      for (int e = 0; e < 12; e++) acc += Wih[o * 12 + e] * We[e * 128 + c];
      WfT[c * 96 + o] = acc * ((o < 64) ? L2E : 2.f * L2E);
    }
    if (tid < 96) {
      float acc = bih[tid];
#pragma unroll
      for (int e = 0; e < 12; e++) acc += Wih[tid * 12 + e] * be[e];
      bf[tid] = acc * ((tid < 64) ? L2E : 2.f * L2E);
    }
  } else {
    int t = (blockIdx.x - 1) * 1024 + tid;
    int bi = t / CIN, c = t % CIN;
    int b = bi >> 10, i = bi & (N_ - 1);
    const float* xr = x + bi * CIN;
    float aq = bq[c], ak = bk[c];
#pragma unroll
    for (int d = 0; d < CIN; d++) {
      float xv = xr[d];
      aq += xv * Wq[c * CIN + d];
      ak += xv * Wk[c * CIN + d];
    }
    int h = c / 12, cc = c - h * 12;
    int bh2 = b * 2 + h;
    q2[(i * 32 + bh2) * 12 + cc] = aq * SCL;   // node-major, prescaled
    k1[(bh2 * N_ + i) * 12 + cc] = ak;         // bh-major (LSE staging)
    k2[(i * 32 + bh2) * 12 + cc] = ak;         // node-major (edge_stats)
    xT[(i * 16 + b) * 24 + c] = xr[c];         // node-major x (gather)
  }
}

// ---------------- fused: row softmax denom (blocks 0..255, 2 rows/thread) + TCN (256..511) ----------------
#define TW 72  // 64 + halo 6 + pad 2
__global__ __launch_bounds__(512) void lse_tcn_kernel(
    const float* __restrict__ q2, const float* __restrict__ k1,
    float* __restrict__ zinv2,
    const float* __restrict__ x,
    const float* __restrict__ c1w0, const float* __restrict__ c1b0,
    const float* __restrict__ c2w0, const float* __restrict__ c2b0,
    const float* __restrict__ dw0, const float* __restrict__ db0,
    const float* __restrict__ c1w1, const float* __restrict__ c1b1,
    const float* __restrict__ c2w1, const float* __restrict__ c2b1,
    float* __restrict__ temporal) {
  __shared__ __align__(16) char smem[53248];
  int tid = threadIdx.x;
  if (blockIdx.x < 256) {
    // ---- LSE: bh = blk>>3, 128 rows per block, 2 rows per thread ----
    float* ks = (float*)smem;                          // 12288 floats (48KB)
    float (*pz)[128] = (float(*)[128])(smem + 49152);  // 8 x 128 (4KB)
    int bh = blockIdx.x >> 3;
    int rg = blockIdx.x & 7;
    const float4* k4 = (const float4*)(k1 + bh * N_ * 12);
    float4* ks4 = (float4*)ks;
    for (int i = tid; i < N_ * 3; i += 512) ks4[i] = k4[i];
    int wave = tid >> 6, lane = tid & 63;
    int row0 = rg * 128 + lane;
    int row1 = row0 + 64;
    float qr0[12], qr1[12];
    const float* qp0 = q2 + ((size_t)row0 * 32 + bh) * 12;
    const float* qp1 = q2 + ((size_t)row1 * 32 + bh) * 12;
#pragma unroll
    for (int c = 0; c < 12; c++) { qr0[c] = qp0[c]; qr1[c] = qp1[c]; }
    __syncthreads();
    const float4* ksr = (const float4*)ks;
    float z0 = 0.f, z1 = 0.f;
    for (int j = wave * 128; j < wave * 128 + 128; j++) {
      float4 k0 = ksr[j * 3], k1v = ksr[j * 3 + 1], k2v = ksr[j * 3 + 2];
      float s0 = qr0[0] * k0.x + qr0[1] * k0.y + qr0[2] * k0.z + qr0[3] * k0.w
               + qr0[4] * k1v.x + qr0[5] * k1v.y + qr0[6] * k1v.z + qr0[7] * k1v.w
               + qr0[8] * k2v.x + qr0[9] * k2v.y + qr0[10] * k2v.z + qr0[11] * k2v.w;
      float s1 = qr1[0] * k0.x + qr1[1] * k0.y + qr1[2] * k0.z + qr1[3] * k0.w
               + qr1[4] * k1v.x + qr1[5] * k1v.y + qr1[6] * k1v.z + qr1[7] * k1v.w
               + qr1[8] * k2v.x + qr1[9] * k2v.y + qr1[10] * k2v.z + qr1[11] * k2v.w;
      z0 += exp2f(s0);    // scores tiny: no max subtraction needed
      z1 += exp2f(s1);
    }
    pz[wave][lane] = z0;
    pz[wave][64 + lane] = z1;
    __syncthreads();
    if (tid < 128) {
      float Z = 0.f;
#pragma unroll
      for (int w2 = 0; w2 < 8; w2++) Z += pz[w2][tid];
      int node = rg * 128 + tid;
      zinv2[node * 32 + bh] = 1.f / Z;
    }
  } else {
    // ---- TCN tile: thread = (g, co); co = tid&63 so in-reads broadcast, stores coalesce
    float* xs   = (float*)smem;        // 24*72
    float* bufA = xs + CIN * TW;       // 64*72
    float* bufB = bufA + 64 * TW;      // 64*72
    int tb = blockIdx.x - 256;
    int b = tb >> 4;
    int t0 = (tb & 15) << 6;
    int co = tid & 63, g = tid >> 6;   // g in 0..7
    for (int i = tid; i < CIN * TW; i += 512) {
      int ln = i / CIN, c = i % CIN;
      int n = t0 - 6 + ln;
      xs[c * TW + ln] = (n >= 0 && n < N_) ? x[(b * N_ + n) * CIN + c] : 0.f;
    }
    __syncthreads();
    // L1
    {
      int lbase = 1 + g * 9;
      float acc[9];
      float bias = c1b0[co];
#pragma unroll
      for (int kk = 0; kk < 9; kk++) acc[kk] = bias;
      const float* wrow = c1w0 + co * 48;
      for (int ci = 0; ci < 24; ci++) {
        float w0 = wrow[ci * 2], w1 = wrow[ci * 2 + 1];
        const float* in = xs + ci * TW + lbase;
        float prev = in[-1];
#pragma unroll
        for (int kk = 0; kk < 9; kk++) { float cur = in[kk]; acc[kk] += w0 * prev + w1 * cur; prev = cur; }
      }
#pragma unroll
      for (int kk = 0; kk < 9; kk++) {
        int ln = lbase + kk;
        if (ln < TW) { int n = t0 - 6 + ln; bufB[co * TW + ln] = (n >= 0) ? fmaxf(acc[kk], 0.f) : 0.f; }
      }
    }
    __syncthreads();
    // L2 + downsample
    {
      int lbase = 2 + g * 9;
      float acc[9], ds[9];
      float bias = c2b0[co], dbias = db0[co];
#pragma unroll
      for (int kk = 0; kk < 9; kk++) { acc[kk] = bias; ds[kk] = dbias; }
      const float* wrow = c2w0 + co * 128;
      for (int ci = 0; ci < 64; ci++) {
        float w0 = wrow[ci * 2], w1 = wrow[ci * 2 + 1];
        const float* in = bufB + ci * TW + lbase;
        float prev = in[-1];
#pragma unroll
        for (int kk = 0; kk < 9; kk++) { float cur = in[kk]; acc[kk] += w0 * prev + w1 * cur; prev = cur; }
      }
      const float* wd = dw0 + co * 24;
      for (int ci = 0; ci < 24; ci++) {
        float wv = wd[ci];
        const float* in = xs + ci * TW + lbase;
#pragma unroll
        for (int kk = 0; kk < 9; kk++) ds[kk] += wv * in[kk];
      }
#pragma unroll
      for (int kk = 0; kk < 9; kk++) {
        int ln = lbase + kk;
        if (ln < TW) {
          int n = t0 - 6 + ln;
          float v = fmaxf(fmaxf(acc[kk], 0.f) + ds[kk], 0.f);
          bufA[co * TW + ln] = (n >= 0) ? v : 0.f;
        }
      }
    }
    __syncthreads();
    // L3: d=2
    {
      int lbase = 4 + g * 9;
      float acc[9];
      float bias = c1b1[co];
#pragma unroll
      for (int kk = 0; kk < 9; kk++) acc[kk] = bias;
      const float* wrow = c1w1 + co * 128;
      for (int ci = 0; ci < 64; ci++) {
        float w0 = wrow[ci * 2], w1 = wrow[ci * 2 + 1];
        const float* in = bufA + ci * TW + lbase;
        float p2 = in[-2], p1 = in[-1];
#pragma unroll
        for (int kk = 0; kk < 9; kk++) { float cur = in[kk]; acc[kk] += w0 * p2 + w1 * cur; p2 = p1; p1 = cur; }
      }
#pragma unroll
      for (int kk = 0; kk < 9; kk++) {
        int ln = lbase + kk;
        if (ln < TW) { int n = t0 - 6 + ln; bufB[co * TW + ln] = (n >= 0) ? fmaxf(acc[kk], 0.f) : 0.f; }
      }
    }
    __syncthreads();
    // L4 + residual
    {
      int lbase = 6 + g * 8;
      float acc[8];
      float bias = c2b1[co];
#pragma unroll
      for (int kk = 0; kk < 8; kk++) acc[kk] = bias;
      const float* wrow = c2w1 + co * 128;
      for (int ci = 0; ci < 64; ci++) {
        float w0 = wrow[ci * 2], w1 = wrow[ci * 2 + 1];
        const float* in = bufB + ci * TW + lbase;
        float p2 = in[-2], p1 = in[-1];
#pragma unroll
        for (int kk = 0; kk < 8; kk++) { float cur = in[kk]; acc[kk] += w0 * p2 + w1 * cur; p2 = p1; p1 = cur; }
      }
#pragma unroll
      for (int kk = 0; kk < 8; kk++) {
        int ln = lbase + kk;
        float v = fmaxf(fmaxf(acc[kk], 0.f) + bufA[co * TW + ln], 0.f);
        temporal[(b * N_ + t0 + ln - 6) * 64 + co] = v;
      }
    }
  }
}

// ---------------- edge stats: one (edge, bh) per thread, fully coalesced, exp2 no-max ----------------
__global__ __launch_bounds__(256) void edge_stats_kernel(
    const float* __restrict__ q2, const float* __restrict__ k2,
    const float* __restrict__ zinv2,
    const int* __restrict__ ei, const float* __restrict__ ewt, int E,
    float* __restrict__ deg) {
  int t = blockIdx.x * 256 + threadIdx.x;
  int e = t >> 5, bh = t & 31;
  if (e >= E) return;
  int src = ei[e], dst = ei[E + e];
  const float4* qp = (const float4*)(q2 + ((size_t)src * 32 + bh) * 12);
  const float4* kp = (const float4*)(k2 + ((size_t)dst * 32 + bh) * 12);
  float s = 0.f;
#pragma unroll
  for (int c4 = 0; c4 < 3; c4++) {
    float4 qv = qp[c4], kv = kp[c4];
    s += qv.x * kv.x + qv.y * kv.y + qv.z * kv.z + qv.w * kv.w;
  }
  float a = exp2f(s) * zinv2[src * 32 + bh];   // q2 prescaled by SCL
  a += __shfl_xor(a, 16);
  a += __shfl_xor(a, 8);
  a += __shfl_xor(a, 4);
  a += __shfl_xor(a, 2);
  a += __shfl_xor(a, 1);
  if (bh == 0) {
    float w = 25.f * ewt[e] * (a * (1.f / 32.f));
    atomicAdd(&deg[src], w);
    atomicAdd(&deg[N_ + dst], w);
  }
}

// ---------------- fused atomic-free gathers (per-node blocks, coalesced xT reads) ----------------
__global__ __launch_bounds__(384) void gather_io_kernel(
    const float* __restrict__ xT, const int* __restrict__ ei, int E,
    const int* __restrict__ rp, const int* __restrict__ cp, const int* __restrict__ eids,
    const float* __restrict__ deg,
    float* __restrict__ t1i, float* __restrict__ t1o) {
  __shared__ int nb[96];
  __shared__ float wv[96];
  bool isOut = blockIdx.x >= N_;
  int node = isOut ? (blockIdx.x - N_) : blockIdx.x;
  int e0 = isOut ? cp[node] : rp[node];
  int e1 = isOut ? cp[node + 1] : rp[node + 1];
  int tid = threadIdx.x;           // tid = b*24 + c
  int b = tid / 24, c = tid % 24;
  float acc = 0.f;
  for (int base = e0; base < e1; base += 96) {
    int m = min(96, e1 - base);
    if (tid < m) {
      if (isOut) {
        int e = eids[base + tid];
        int sn = ei[e];
        nb[tid] = sn;
        wv[tid] = __builtin_amdgcn_rcpf(deg[sn]);
      } else {
        int d = ei[E + base + tid];
        nb[tid] = d;
        wv[tid] = __builtin_amdgcn_rcpf(deg[N_ + d]);
      }
    }
    __syncthreads();
    for (int t = 0; t < m; t++) acc += xT[nb[t] * 384 + tid] * wv[t];   // 1.5KB coalesced per edge
    __syncthreads();
  }
  float* dst = isOut ? t1o : t1i;
  dst[(b * N_ + node) * CIN + c] = acc;
}

// ---------------- fused spatial + xp: 32-node tiles, 512 blocks ----------------
__global__ __launch_bounds__(384) void spatxp_kernel(
    const float* __restrict__ x, const float* __restrict__ t1o, const float* __restrict__ t1i,
    const float* __restrict__ Wd, const float* __restrict__ bd,
    const float* __restrict__ temporal,
    const float* __restrict__ WfT, const float* __restrict__ bf,
    float* __restrict__ xp) {
  __shared__ float tmp_s[32 * 64];   // temporal tile [nl][c] 8 KB
  __shared__ float spat_s[32 * 64];  // 8 KB
  __shared__ float xs3[3 * 32 * 24]; // x | t1o | t1i tiles [nl][d] 9 KB
  int b = blockIdx.x >> 5;
  int n0 = (blockIdx.x & 31) << 5;
  int tid = threadIdx.x;
  {
    const float4* t4 = (const float4*)(temporal + (size_t)(b * N_ + n0) * 64);
    float4* d4 = (float4*)tmp_s;
    for (int i = tid; i < 512; i += 384) d4[i] = t4[i];
    size_t base = (size_t)(b * N_ + n0) * 24;
    const float4* xsrc = (const float4*)(x + base);
    const float4* asrc = (const float4*)(t1o + base);
    const float4* bsrc = (const float4*)(t1i + base);
    float4* xd = (float4*)xs3;
    if (tid < 192) {                 // 192 f4 each
      xd[tid] = xsrc[tid];
      xd[192 + tid] = asrc[tid];
      xd[384 + tid] = bsrc[tid];
    }
  }
  __syncthreads();
  for (int idx = tid; idx < 2048; idx += 384) {
    int nl = idx >> 6, o = idx & 63;
    const float* xr = xs3 + nl * 24;
    const float* ar = xs3 + 768 + nl * 24;
    const float* br = xs3 + 1536 + nl * 24;
    float acc = bd[o];
#pragma unroll
    for (int d = 0; d < CIN; d++) {
      acc += xr[d] * (Wd[d * 64 + o] + Wd[3072 + d * 64 + o]);
      acc += ar[d] * Wd[1536 + d * 64 + o];
      acc += br[d] * Wd[4608 + d * 64 + o];
    }
    spat_s[nl * 64 + o] = fmaxf(acc, 0.f);
  }
  __syncthreads();
  {
    int g = tid / 96, o = tid - g * 96;   // g in 0..3, 8 nodes each
    float acc[8];
#pragma unroll
    for (int kk = 0; kk < 8; kk++) acc[kk] = bf[o];
    const float* tr = tmp_s + g * 8 * 64;
    const float* sr = spat_s + g * 8 * 64;
    for (int c = 0; c < 64; c++) {
      float w1 = WfT[c * 96 + o];
      float w2 = WfT[(64 + c) * 96 + o];
#pragma unroll
      for (int kk = 0; kk < 8; kk++) {
        acc[kk] = fmaf(tr[kk * 64 + c], w1, fmaf(sr[kk * 64 + c], w2, acc[kk]));
      }
    }
#pragma unroll
    for (int kk = 0; kk < 8; kk++)
      xp[(size_t)(b * N_ + n0 + g * 8 + kk) * 96 + o] = acc[kk];
  }
}

// ---------------- GRU scan: 16 blocks, LDS-broadcast h, single-chain packed dots ----------------
#define CHUNK 64
__global__ __launch_bounds__(256) void gru_kernel(
    const float* __restrict__ xp, const float* __restrict__ Whh,
    const float* __restrict__ bhh, const float* __restrict__ Wdec,
    const float* __restrict__ bdec, float* __restrict__ out) {
  __shared__ float xbuf[2][(CHUNK + 1) * 96];   // 65 rows: unconditional ln+1 prefetch
  __shared__ float hbuf[2][CHUNK * 36];         // 18 KB
  __shared__ float wdec_s[12 * 36];
  __shared__ float bdec_s[12];
  int b = blockIdx.x, tid = threadIdx.x;
  int wave = tid >> 6, j = tid & 63, jl = j & 31, hi = j >> 5;
  const float* xpb = xp + (size_t)b * N_ * 96;
  {
    const float4* s4 = (const float4*)xpb;
    float4* d4 = (float4*)xbuf[0];
    for (int i = tid; i < CHUNK * 24; i += 256) d4[i] = s4[i];
    if (tid < 12) bdec_s[tid] = bdec[tid];
    for (int i = tid; i < 384; i += 256) wdec_s[(i >> 5) * 36 + (i & 31)] = Wdec[i];
    // zero the 65th row of both buffers (read by the dead last-iteration prefetch)
    if (tid < 96) { xbuf[0][CHUNK * 96 + tid] = 0.f; xbuf[1][CHUNK * 96 + tid] = 0.f; }
  }
  f2 wA2[16], wB2[16];
  float bA = 0.f, bB = 0.f, hloc = 0.f;
  int xoff = hi ? (32 + jl) : jl;
  if (wave == 0) {
    int rowA = hi ? (32 + jl) : jl;
#pragma unroll
    for (int i = 0; i < 16; i++) {
      wA2[i] = f2{L2E * Whh[rowA * 32 + 2 * i], L2E * Whh[rowA * 32 + 2 * i + 1]};
      wB2[i] = f2{2.f * L2E * Whh[(64 + jl) * 32 + 2 * i], 2.f * L2E * Whh[(64 + jl) * 32 + 2 * i + 1]};
    }
    bA = L2E * bhh[rowA];
    bB = 2.f * L2E * bhh[64 + jl];
  }
  float4 hv4[8];
#pragma unroll
  for (int i = 0; i < 8; i++) hv4[i] = float4{0.f, 0.f, 0.f, 0.f};
  __syncthreads();
  for (int c = 0; c < 16; c++) {
    if (wave == 0) {
      const float* buf = xbuf[c & 1];
      float* hb = hbuf[c & 1];
      float xga = buf[xoff] + bA;
      float xnv = buf[64 + jl];
      for (int ln = 0; ln < CHUNK; ln++) {
        // unconditional prefetch (row 64 exists; value dead on last iteration)
        float nxga = buf[(ln + 1) * 96 + xoff] + bA;
        float nxnv = buf[(ln + 1) * 96 + 64 + jl];
        f2 aA = f2{xga, 0.f};
        f2 aB = f2{bB, 0.f};
#pragma unroll
        for (int i = 0; i < 8; i++) {
          f2 h01 = f2{hv4[i].x, hv4[i].y};
          f2 h23 = f2{hv4[i].z, hv4[i].w};
          aA = __builtin_elementwise_fma(wA2[2 * i], h01, aA);
          aB = __builtin_elementwise_fma(wB2[2 * i], h01, aB);
          aA = __builtin_elementwise_fma(wA2[2 * i + 1], h23, aA);
          aB = __builtin_elementwise_fma(wB2[2 * i + 1], h23, aB);
        }
        float gA = aA.x + aA.y;   // low: r-arg, high: z-arg (x log2e)
        float gB = aB.x + aB.y;   // n-dot + bias (x 2log2e)
        float sg = __builtin_amdgcn_rcpf(1.f + exp2f(-gA));   // low: r, high: z
#if __has_builtin(__builtin_amdgcn_permlane32_swap)
        uvec2 sw = __builtin_amdgcn_permlane32_swap(__float_as_uint(sg), __float_as_uint(sg), false, false);
        float zv = __uint_as_float(sw.y);    // low lanes: z from high half
#else
        float zv = __shfl_xor(sg, 32);
#endif
        float pre = fmaf(sg, gB, xnv);
        float t = exp2f(pre);
        float nn = fmaf(-2.f, __builtin_amdgcn_rcpf(t + 1.f), 1.f);  // tanh
        hloc = fmaf(zv, hloc - nn, nn);      // high lanes: bounded junk, never read
        if (j < 32) hb[ln * 36 + jl] = hloc;
        const float4* hrow = (const float4*)(hb + ln * 36);
#pragma unroll
        for (int i = 0; i < 8; i++) hv4[i] = hrow[i];
        xga = nxga; xnv = nxnv;
      }
    } else {
      int t64 = tid - 64;
      if (c + 1 < 16) {
        const float4* s4 = (const float4*)(xpb + (size_t)(c + 1) * CHUNK * 96);
        float4* d4 = (float4*)xbuf[(c + 1) & 1];
        for (int i = t64; i < CHUNK * 24; i += 192) d4[i] = s4[i];
      }
      if (c > 0) {
        const float* hb = hbuf[(c - 1) & 1];
        int n0b = (c - 1) * CHUNK;
#pragma unroll
        for (int qq = 0; qq < 4; qq++) {
          int idx = qq * 192 + t64;             // < 768 = 64 nodes x 12 outs
          int nl = idx / 12, o = idx - nl * 12;
          const float4* h4 = (const float4*)(hb + nl * 36);
          const float4* w4 = (const float4*)(wdec_s + o * 36);
          float acc = bdec_s[o];
#pragma unroll
          for (int i = 0; i < 8; i++) {
            float4 hv = h4[i], wv = w4[i];
            acc += fmaxf(hv.x, 0.f) * wv.x + fmaxf(hv.y, 0.f) * wv.y +
                   fmaxf(hv.z, 0.f) * wv.z + fmaxf(hv.w, 0.f) * wv.w;
          }
          out[(size_t)(b * N_ + n0b + nl) * 12 + o] = acc;
        }
      }
    }
    __syncthreads();
  }
  // decode last chunk
  {
    const float* hb = hbuf[1];   // chunk 15
    int n0b = 15 * CHUNK;
#pragma unroll
    for (int qq = 0; qq < 3; qq++) {
      int idx = qq * 256 + tid;
      int nl = idx / 12, o = idx - nl * 12;
      const float4* h4 = (const float4*)(hb + nl * 36);
      const float4* w4 = (const float4*)(wdec_s + o * 36);
      float acc = bdec_s[o];
#pragma unroll
      for (int i = 0; i < 8; i++) {
        float4 hv = h4[i], wv = w4[i];
        acc += fmaxf(hv.x, 0.f) * wv.x + fmaxf(hv.y, 0.f) * wv.y +
               fmaxf(hv.z, 0.f) * wv.z + fmaxf(hv.w, 0.f) * wv.w;
      }
      out[(size_t)(b * N_ + n0b + nl) * 12 + o] = acc;
    }
  }
}

extern "C" void kernel_launch(void* const* d_in, const int* in_sizes, int n_in,
                              void* d_out, int out_size, void* d_ws, size_t ws_size,
                              hipStream_t stream) {
  const float* x    = (const float*)d_in[0];
  const int*   ei   = (const int*)d_in[2];
  const float* ewt  = (const float*)d_in[3];
  const float* Wq   = (const float*)d_in[4];
  const float* bq   = (const float*)d_in[5];
  const float* Wk   = (const float*)d_in[6];
  const float* bk   = (const float*)d_in[7];
  const float* Wd   = (const float*)d_in[8];
  const float* bd   = (const float*)d_in[9];
  const float* c1w0 = (const float*)d_in[10];
  const float* c1b0 = (const float*)d_in[11];
  const float* c2w0 = (const float*)d_in[12];
  const float* c2b0 = (const float*)d_in[13];
  const float* dw0  = (const float*)d_in[14];
  const float* db0  = (const float*)d_in[15];
  const float* c1w1 = (const float*)d_in[16];
  const float* c1b1 = (const float*)d_in[17];
  const float* c2w1 = (const float*)d_in[18];
  const float* c2b1 = (const float*)d_in[19];
  const float* We   = (const float*)d_in[20];
  const float* be   = (const float*)d_in[21];
  const float* Wih  = (const float*)d_in[22];
  const float* Whh  = (const float*)d_in[23];
  const float* bih  = (const float*)d_in[24];
  const float* bhh  = (const float*)d_in[25];
  const float* Wdec = (const float*)d_in[26];
  const float* bdec = (const float*)d_in[27];
  float* out = (float*)d_out;
  float* w = (float*)d_ws;
  const int E = in_sizes[2] / 2;

  float* q2    = w + OFF_Q2;
  float* k1    = w + OFF_K1;
  float* k2    = w + OFF_K2;
  float* zinv2 = w + OFF_ZI;
  float* deg   = w + OFF_DEG;
  float* t1o   = w + OFF_Q2;   // reuse after edge_stats
  float* t1i   = w + OFF_K1;   // reuse after lse
  float* temp  = w + OFF_TEMP;
  float* WfT   = w + OFF_WFT;
  float* bf    = w + OFF_BF;
  float* xp    = w + OFF_XP;
  float* xT    = w + OFF_XT;
  int* ib   = (int*)(w + OFF_INT);
  int* rp   = ib;            // 1025
  int* cp   = ib + 1028;     // 1025
  int* eids = ib + 2056;     // E

  qk_prep_kernel<<<385, 1024, 0, stream>>>(x, Wq, bq, Wk, bk, q2, k1, k2, xT,
                                           ei, E, deg, rp, cp, eids,
                                           We, be, Wih, bih, WfT, bf);
  lse_tcn_kernel<<<512, 512, 0, stream>>>(q2, k1, zinv2, x,
                                          c1w0, c1b0, c2w0, c2b0, dw0, db0,
                                          c1w1, c1b1, c2w1, c2b1, temp);
  edge_stats_kernel<<<(E * 32 + 255) / 256, 256, 0, stream>>>(q2, k2, zinv2, ei, ewt, E, deg);
  gather_io_kernel<<<2 * N_, 384, 0, stream>>>(xT, ei, E, rp, cp, eids, deg, t1i, t1o);
  spatxp_kernel<<<B_ * 32, 384, 0, stream>>>(x, t1o, t1i, Wd, bd, temp, WfT, bf, xp);
  gru_kernel<<<B_, 256, 0, stream>>>(xp, Whh, bhh, Wdec, bdec, out);
}

// Round 13
// 350.128 us; speedup vs baseline: 1.0503x; 1.0503x over previous
//
#include <hip/hip_runtime.h>
#include <hip/hip_bf16.h>

// Sizes (compile-time)
#define B_ 16
#define N_ 1024
#define CIN 24
#define EMB_ 64
#define HID_ 32
#define OUT_ 12
#define BH_ 32            // B*HEADS
#define RSQRT12 0.28867513459481287f
#define L2E 1.4426950408889634f
#define SCL (RSQRT12 * L2E)   // folded into q2 at write time

typedef unsigned uvec2 __attribute__((ext_vector_type(2)));
typedef float f2 __attribute__((ext_vector_type(2)));

// ---------------- workspace layout (floats) ----------------
#define OFF_Q2     0              // 393216  q node-major [node][bh][12], prescaled by SCL (reused as t1o)
#define OFF_K1     393216         // 393216  k bh-major   [bh][node][12] (reused as t1i)
#define OFF_K2     786432         // 393216  k node-major [node][bh][12]
#define OFF_ZI     1212416        // 32768   zinv2 [node][bh]
#define OFF_DEG    1245184        // 2048
#define OFF_INT    1247232        // int area (rp/cp/eids) ~24K ints
#define OFF_TEMP   1271296        // 1048576
#define OFF_WFT    2319872        // 12288
#define OFF_BF     2332160        // 128
#define OFF_XP     2332288        // 1572864
#define OFF_XT     3905152        // 393216  x node-major [node][b][c]

// ---------------- fused: qk projection (blocks 1..384) + graph prep/wfold (block 0) ----------------
__global__ __launch_bounds__(1024) void qk_prep_kernel(
    const float* __restrict__ x, const float* __restrict__ Wq, const float* __restrict__ bq,
    const float* __restrict__ Wk, const float* __restrict__ bk,
    float* __restrict__ q2, float* __restrict__ k1, float* __restrict__ k2,
    float* __restrict__ xT,
    const int* __restrict__ ei, int E,
    float* __restrict__ deg, int* __restrict__ rp, int* __restrict__ cp,
    int* __restrict__ eids,
    const float* __restrict__ We, const float* __restrict__ be,
    const float* __restrict__ Wih, const float* __restrict__ bih,
    float* __restrict__ WfT, float* __restrict__ bf) {
  __shared__ int cntL[1024];
  __shared__ int sL[1024];
  __shared__ int offL[1024];
  int tid = threadIdx.x;
  if (blockIdx.x == 0) {
    deg[tid] = 0.f; deg[N_ + tid] = 0.f;
    cntL[tid] = 0;
    { int lo = 0, hi2 = E;
      while (lo < hi2) { int mid = (lo + hi2) >> 1; if (ei[mid] < tid) lo = mid + 1; else hi2 = mid; }
      rp[tid] = lo; }
    if (tid == 0) rp[N_] = E;
    __syncthreads();
    for (int e = tid; e < E; e += 1024) atomicAdd(&cntL[ei[E + e]], 1);
    __syncthreads();
    int my = cntL[tid];
    sL[tid] = my;
    __syncthreads();
    for (int d = 1; d < 1024; d <<= 1) {
      int v = (tid >= d) ? sL[tid - d] : 0;
      __syncthreads();
      sL[tid] += v;
      __syncthreads();
    }
    int excl = sL[tid] - my;
    cp[tid] = excl;
    offL[tid] = excl;
    if (tid == 1023) cp[1024] = sL[tid];
    __syncthreads();
    for (int e = tid; e < E; e += 1024) {
      int p = atomicAdd(&offL[ei[E + e]], 1);
      eids[p] = e;
    }
    for (int i = tid; i < 128 * 96; i += 1024) {
      int o = i % 96, c = i / 96;
      float acc = 0.f;
#pragma unroll
      for (int e = 0; e < 12; e++) acc += Wih[o * 12 + e] * We[e * 128 + c];
      WfT[c * 96 + o] = acc * ((o < 64) ? L2E : 2.f * L2E);
    }
    if (tid < 96) {
      float acc = bih[tid];
#pragma unroll
      for (int e = 0; e < 12; e++) acc += Wih[tid * 12 + e] * be[e];
      bf[tid] = acc * ((tid < 64) ? L2E : 2.f * L2E);
    }
  } else {
    int t = (blockIdx.x - 1) * 1024 + tid;
    int bi = t / CIN, c = t % CIN;
    int b = bi >> 10, i = bi & (N_ - 1);
    const float* xr = x + bi * CIN;
    float aq = bq[c], ak = bk[c];
#pragma unroll
    for (int d = 0; d < CIN; d++) {
      float xv = xr[d];
      aq += xv * Wq[c * CIN + d];
      ak += xv * Wk[c * CIN + d];
    }
    int h = c / 12, cc = c - h * 12;
    int bh2 = b * 2 + h;
    q2[(i * 32 + bh2) * 12 + cc] = aq * SCL;   // node-major, prescaled
    k1[(bh2 * N_ + i) * 12 + cc] = ak;         // bh-major (LSE staging)
    k2[(i * 32 + bh2) * 12 + cc] = ak;         // node-major (edge_stats)
    xT[(i * 16 + b) * 24 + c] = xr[c];         // node-major x (gather)
  }
}

// ---------------- fused: row softmax denom (blocks 0..255, 2 rows/thread) + TCN (256..511) ----------------
#define TW 72  // 64 + halo 6 + pad 2
__global__ __launch_bounds__(512) void lse_tcn_kernel(
    const float* __restrict__ q2, const float* __restrict__ k1,
    float* __restrict__ zinv2,
    const float* __restrict__ x,
    const float* __restrict__ c1w0, const float* __restrict__ c1b0,
    const float* __restrict__ c2w0, const float* __restrict__ c2b0,
    const float* __restrict__ dw0, const float* __restrict__ db0,
    const float* __restrict__ c1w1, const float* __restrict__ c1b1,
    const float* __restrict__ c2w1, const float* __restrict__ c2b1,
    float* __restrict__ temporal) {
  __shared__ __align__(16) char smem[53248];
  int tid = threadIdx.x;
  if (blockIdx.x < 256) {
    // ---- LSE: bh = blk>>3, 128 rows per block, 2 rows per thread ----
    float* ks = (float*)smem;                          // 12288 floats (48KB)
    float (*pz)[128] = (float(*)[128])(smem + 49152);  // 8 x 128 (4KB)
    int bh = blockIdx.x >> 3;
    int rg = blockIdx.x & 7;
    const float4* k4 = (const float4*)(k1 + bh * N_ * 12);
    float4* ks4 = (float4*)ks;
    for (int i = tid; i < N_ * 3; i += 512) ks4[i] = k4[i];
    int wave = tid >> 6, lane = tid & 63;
    int row0 = rg * 128 + lane;
    int row1 = row0 + 64;
    float qr0[12], qr1[12];
    const float* qp0 = q2 + ((size_t)row0 * 32 + bh) * 12;
    const float* qp1 = q2 + ((size_t)row1 * 32 + bh) * 12;
#pragma unroll
    for (int c = 0; c < 12; c++) { qr0[c] = qp0[c]; qr1[c] = qp1[c]; }
    __syncthreads();
    const float4* ksr = (const float4*)ks;
    float z0 = 0.f, z1 = 0.f;
    for (int j = wave * 128; j < wave * 128 + 128; j++) {
      float4 k0 = ksr[j * 3], k1v = ksr[j * 3 + 1], k2v = ksr[j * 3 + 2];
      float s0 = qr0[0] * k0.x + qr0[1] * k0.y + qr0[2] * k0.z + qr0[3] * k0.w
               + qr0[4] * k1v.x + qr0[5] * k1v.y + qr0[6] * k1v.z + qr0[7] * k1v.w
               + qr0[8] * k2v.x + qr0[9] * k2v.y + qr0[10] * k2v.z + qr0[11] * k2v.w;
      float s1 = qr1[0] * k0.x + qr1[1] * k0.y + qr1[2] * k0.z + qr1[3] * k0.w
               + qr1[4] * k1v.x + qr1[5] * k1v.y + qr1[6] * k1v.z + qr1[7] * k1v.w
               + qr1[8] * k2v.x + qr1[9] * k2v.y + qr1[10] * k2v.z + qr1[11] * k2v.w;
      z0 += exp2f(s0);    // scores tiny: no max subtraction needed
      z1 += exp2f(s1);
    }
    pz[wave][lane] = z0;
    pz[wave][64 + lane] = z1;
    __syncthreads();
    if (tid < 128) {
      float Z = 0.f;
#pragma unroll
      for (int w2 = 0; w2 < 8; w2++) Z += pz[w2][tid];
      int node = rg * 128 + tid;
      zinv2[node * 32 + bh] = 1.f / Z;
    }
  } else {
    // ---- TCN tile: thread = (g, co); co = tid&63 so in-reads broadcast, stores coalesce
    float* xs   = (float*)smem;        // 24*72
    float* bufA = xs + CIN * TW;       // 64*72
    float* bufB = bufA + 64 * TW;      // 64*72
    int tb = blockIdx.x - 256;
    int b = tb >> 4;
    int t0 = (tb & 15) << 6;
    int co = tid & 63, g = tid >> 6;   // g in 0..7
    for (int i = tid; i < CIN * TW; i += 512) {
      int ln = i / CIN, c = i % CIN;
      int n = t0 - 6 + ln;
      xs[c * TW + ln] = (n >= 0 && n < N_) ? x[(b * N_ + n) * CIN + c] : 0.f;
    }
    __syncthreads();
    // L1
    {
      int lbase = 1 + g * 9;
      float acc[9];
      float bias = c1b0[co];
#pragma unroll
      for (int kk = 0; kk < 9; kk++) acc[kk] = bias;
      const float* wrow = c1w0 + co * 48;
      for (int ci = 0; ci < 24; ci++) {
        float w0 = wrow[ci * 2], w1 = wrow[ci * 2 + 1];
        const float* in = xs + ci * TW + lbase;
        float prev = in[-1];
#pragma unroll
        for (int kk = 0; kk < 9; kk++) { float cur = in[kk]; acc[kk] += w0 * prev + w1 * cur; prev = cur; }
      }
#pragma unroll
      for (int kk = 0; kk < 9; kk++) {
        int ln = lbase + kk;
        if (ln < TW) { int n = t0 - 6 + ln; bufB[co * TW + ln] = (n >= 0) ? fmaxf(acc[kk], 0.f) : 0.f; }
      }
    }
    __syncthreads();
    // L2 + downsample
    {
      int lbase = 2 + g * 9;
      float acc[9], ds[9];
      float bias = c2b0[co], dbias = db0[co];
#pragma unroll
      for (int kk = 0; kk < 9; kk++) { acc[kk] = bias; ds[kk] = dbias; }
      const float* wrow = c2w0 + co * 128;
      for (int ci = 0; ci < 64; ci++) {
        float w0 = wrow[ci * 2], w1 = wrow[ci * 2 + 1];
        const float* in = bufB + ci * TW + lbase;
        float prev = in[-1];
#pragma unroll
        for (int kk = 0; kk < 9; kk++) { float cur = in[kk]; acc[kk] += w0 * prev + w1 * cur; prev = cur; }
      }
      const float* wd = dw0 + co * 24;
      for (int ci = 0; ci < 24; ci++) {
        float wv = wd[ci];
        const float* in = xs + ci * TW + lbase;
#pragma unroll
        for (int kk = 0; kk < 9; kk++) ds[kk] += wv * in[kk];
      }
#pragma unroll
      for (int kk = 0; kk < 9; kk++) {
        int ln = lbase + kk;
        if (ln < TW) {
          int n = t0 - 6 + ln;
          float v = fmaxf(fmaxf(acc[kk], 0.f) + ds[kk], 0.f);
          bufA[co * TW + ln] = (n >= 0) ? v : 0.f;
        }
      }
    }
    __syncthreads();
    // L3: d=2
    {
      int lbase = 4 + g * 9;
      float acc[9];
      float bias = c1b1[co];
#pragma unroll
      for (int kk = 0; kk < 9; kk++) acc[kk] = bias;
      const float* wrow = c1w1 + co * 128;
      for (int ci = 0; ci < 64; ci++) {
        float w0 = wrow[ci * 2], w1 = wrow[ci * 2 + 1];
        const float* in = bufA + ci * TW + lbase;
        float p2 = in[-2], p1 = in[-1];
#pragma unroll
        for (int kk = 0; kk < 9; kk++) { float cur = in[kk]; acc[kk] += w0 * p2 + w1 * cur; p2 = p1; p1 = cur; }
      }
#pragma unroll
      for (int kk = 0; kk < 9; kk++) {
        int ln = lbase + kk;
        if (ln < TW) { int n = t0 - 6 + ln; bufB[co * TW + ln] = (n >= 0) ? fmaxf(acc[kk], 0.f) : 0.f; }
      }
    }
    __syncthreads();
    // L4 + residual
    {
      int lbase = 6 + g * 8;
      float acc[8];
      float bias = c2b1[co];
#pragma unroll
      for (int kk = 0; kk < 8; kk++) acc[kk] = bias;
      const float* wrow = c2w1 + co * 128;
      for (int ci = 0; ci < 64; ci++) {
        float w0 = wrow[ci * 2], w1 = wrow[ci * 2 + 1];
        const float* in = bufB + ci * TW + lbase;
        float p2 = in[-2], p1 = in[-1];
#pragma unroll
        for (int kk = 0; kk < 8; kk++) { float cur = in[kk]; acc[kk] += w0 * p2 + w1 * cur; p2 = p1; p1 = cur; }
      }
#pragma unroll
      for (int kk = 0; kk < 8; kk++) {
        int ln = lbase + kk;
        float v = fmaxf(fmaxf(acc[kk], 0.f) + bufA[co * TW + ln], 0.f);
        temporal[(b * N_ + t0 + ln - 6) * 64 + co] = v;
      }
    }
  }
}

// ---------------- edge stats: one (edge, bh) per thread, fully coalesced, exp2 no-max ----------------
__global__ __launch_bounds__(256) void edge_stats_kernel(
    const float* __restrict__ q2, const float* __restrict__ k2,
    const float* __restrict__ zinv2,
    const int* __restrict__ ei, const float* __restrict__ ewt, int E,
    float* __restrict__ deg) {
  int t = blockIdx.x * 256 + threadIdx.x;
  int e = t >> 5, bh = t & 31;
  if (e >= E) return;
  int src = ei[e], dst = ei[E + e];
  const float4* qp = (const float4*)(q2 + ((size_t)src * 32 + bh) * 12);
  const float4* kp = (const float4*)(k2 + ((size_t)dst * 32 + bh) * 12);
  float s = 0.f;
#pragma unroll
  for (int c4 = 0; c4 < 3; c4++) {
    float4 qv = qp[c4], kv = kp[c4];
    s += qv.x * kv.x + qv.y * kv.y + qv.z * kv.z + qv.w * kv.w;
  }
  float a = exp2f(s) * zinv2[src * 32 + bh];   // q2 prescaled by SCL
  a += __shfl_xor(a, 16);
  a += __shfl_xor(a, 8);
  a += __shfl_xor(a, 4);
  a += __shfl_xor(a, 2);
  a += __shfl_xor(a, 1);
  if (bh == 0) {
    float w = 25.f * ewt[e] * (a * (1.f / 32.f));
    atomicAdd(&deg[src], w);
    atomicAdd(&deg[N_ + dst], w);
  }
}

// ---------------- fused atomic-free gathers (per-node blocks, coalesced xT reads) ----------------
__global__ __launch_bounds__(384) void gather_io_kernel(
    const float* __restrict__ xT, const int* __restrict__ ei, int E,
    const int* __restrict__ rp, const int* __restrict__ cp, const int* __restrict__ eids,
    const float* __restrict__ deg,
    float* __restrict__ t1i, float* __restrict__ t1o) {
  __shared__ int nb[96];
  __shared__ float wv[96];
  bool isOut = blockIdx.x >= N_;
  int node = isOut ? (blockIdx.x - N_) : blockIdx.x;
  int e0 = isOut ? cp[node] : rp[node];
  int e1 = isOut ? cp[node + 1] : rp[node + 1];
  int tid = threadIdx.x;           // tid = b*24 + c
  int b = tid / 24, c = tid % 24;
  float acc = 0.f;
  for (int base = e0; base < e1; base += 96) {
    int m = min(96, e1 - base);
    if (tid < m) {
      if (isOut) {
        int e = eids[base + tid];
        int sn = ei[e];
        nb[tid] = sn;
        wv[tid] = __builtin_amdgcn_rcpf(deg[sn]);
      } else {
        int d = ei[E + base + tid];
        nb[tid] = d;
        wv[tid] = __builtin_amdgcn_rcpf(deg[N_ + d]);
      }
    }
    __syncthreads();
    for (int t = 0; t < m; t++) acc += xT[nb[t] * 384 + tid] * wv[t];   // 1.5KB coalesced per edge
    __syncthreads();
  }
  float* dst = isOut ? t1o : t1i;
  dst[(b * N_ + node) * CIN + c] = acc;
}

// ---------------- fused spatial + xp: 32-node tiles, 512 blocks ----------------
__global__ __launch_bounds__(384) void spatxp_kernel(
    const float* __restrict__ x, const float* __restrict__ t1o, const float* __restrict__ t1i,
    const float* __restrict__ Wd, const float* __restrict__ bd,
    const float* __restrict__ temporal,
    const float* __restrict__ WfT, const float* __restrict__ bf,
    float* __restrict__ xp) {
  __shared__ float tmp_s[32 * 64];   // temporal tile [nl][c] 8 KB
  __shared__ float spat_s[32 * 64];  // 8 KB
  __shared__ float xs3[3 * 32 * 24]; // x | t1o | t1i tiles [nl][d] 9 KB
  int b = blockIdx.x >> 5;
  int n0 = (blockIdx.x & 31) << 5;
  int tid = threadIdx.x;
  {
    const float4* t4 = (const float4*)(temporal + (size_t)(b * N_ + n0) * 64);
    float4* d4 = (float4*)tmp_s;
    for (int i = tid; i < 512; i += 384) d4[i] = t4[i];
    size_t base = (size_t)(b * N_ + n0) * 24;
    const float4* xsrc = (const float4*)(x + base);
    const float4* asrc = (const float4*)(t1o + base);
    const float4* bsrc = (const float4*)(t1i + base);
    float4* xd = (float4*)xs3;
    if (tid < 192) {                 // 192 f4 each
      xd[tid] = xsrc[tid];
      xd[192 + tid] = asrc[tid];
      xd[384 + tid] = bsrc[tid];
    }
  }
  __syncthreads();
  for (int idx = tid; idx < 2048; idx += 384) {
    int nl = idx >> 6, o = idx & 63;
    const float* xr = xs3 + nl * 24;
    const float* ar = xs3 + 768 + nl * 24;
    const float* br = xs3 + 1536 + nl * 24;
    float acc = bd[o];
#pragma unroll
    for (int d = 0; d < CIN; d++) {
      acc += xr[d] * (Wd[d * 64 + o] + Wd[3072 + d * 64 + o]);
      acc += ar[d] * Wd[1536 + d * 64 + o];
      acc += br[d] * Wd[4608 + d * 64 + o];
    }
    spat_s[nl * 64 + o] = fmaxf(acc, 0.f);
  }
  __syncthreads();
  {
    int g = tid / 96, o = tid - g * 96;   // g in 0..3, 8 nodes each
    float acc[8];
#pragma unroll
    for (int kk = 0; kk < 8; kk++) acc[kk] = bf[o];
    const float* tr = tmp_s + g * 8 * 64;
    const float* sr = spat_s + g * 8 * 64;
    for (int c = 0; c < 64; c++) {
      float w1 = WfT[c * 96 + o];
      float w2 = WfT[(64 + c) * 96 + o];
#pragma unroll
      for (int kk = 0; kk < 8; kk++) {
        acc[kk] = fmaf(tr[kk * 64 + c], w1, fmaf(sr[kk * 64 + c], w2, acc[kk]));
      }
    }
#pragma unroll
    for (int kk = 0; kk < 8; kk++)
      xp[(size_t)(b * N_ + n0 + g * 8 + kk) * 96 + o] = acc[kk];
  }
}

// ---------------- GRU scan: 16 blocks, LDS-broadcast h, single-chain packed dots (r10 proven) ----------------
#define CHUNK 64
__global__ __launch_bounds__(256) void gru_kernel(
    const float* __restrict__ xp, const float* __restrict__ Whh,
    const float* __restrict__ bhh, const float* __restrict__ Wdec,
    const float* __restrict__ bdec, float* __restrict__ out) {
  __shared__ float xbuf[2][CHUNK * 96];   // 48 KB
  __shared__ float hbuf[2][CHUNK * 36];   // 18 KB
  __shared__ float wdec_s[12 * 36];
  __shared__ float bdec_s[12];
  int b = blockIdx.x, tid = threadIdx.x;
  int wave = tid >> 6, j = tid & 63, jl = j & 31, hi = j >> 5;
  const float* xpb = xp + (size_t)b * N_ * 96;
  {
    const float4* s4 = (const float4*)xpb;
    float4* d4 = (float4*)xbuf[0];
    for (int i = tid; i < CHUNK * 24; i += 256) d4[i] = s4[i];
    if (tid < 12) bdec_s[tid] = bdec[tid];
    for (int i = tid; i < 384; i += 256) wdec_s[(i >> 5) * 36 + (i & 31)] = Wdec[i];
  }
  f2 wA2[16], wB2[16];
  float bA = 0.f, bB = 0.f, hloc = 0.f;
  int xoff = hi ? (32 + jl) : jl;
  if (wave == 0) {
    int rowA = hi ? (32 + jl) : jl;
#pragma unroll
    for (int i = 0; i < 16; i++) {
      wA2[i] = f2{L2E * Whh[rowA * 32 + 2 * i], L2E * Whh[rowA * 32 + 2 * i + 1]};
      wB2[i] = f2{2.f * L2E * Whh[(64 + jl) * 32 + 2 * i], 2.f * L2E * Whh[(64 + jl) * 32 + 2 * i + 1]};
    }
    bA = L2E * bhh[rowA];
    bB = 2.f * L2E * bhh[64 + jl];
  }
  float4 hv4[8];
#pragma unroll
  for (int i = 0; i < 8; i++) hv4[i] = float4{0.f, 0.f, 0.f, 0.f};
  __syncthreads();
  for (int c = 0; c < 16; c++) {
    if (wave == 0) {
      const float* buf = xbuf[c & 1];
      float* hb = hbuf[c & 1];
      float xga = buf[xoff] + bA;
      float xnv = buf[64 + jl];
      for (int ln = 0; ln < CHUNK; ln++) {
        float nxga = 0.f, nxnv = 0.f;
        if (ln + 1 < CHUNK) {
          nxga = buf[(ln + 1) * 96 + xoff] + bA;
          nxnv = buf[(ln + 1) * 96 + 64 + jl];
        }
        f2 aA = f2{xga, 0.f};
        f2 aB = f2{bB, 0.f};
#pragma unroll
        for (int i = 0; i < 8; i++) {
          f2 h01 = f2{hv4[i].x, hv4[i].y};
          f2 h23 = f2{hv4[i].z, hv4[i].w};
          aA = __builtin_elementwise_fma(wA2[2 * i], h01, aA);
          aB = __builtin_elementwise_fma(wB2[2 * i], h01, aB);
          aA = __builtin_elementwise_fma(wA2[2 * i + 1], h23, aA);
          aB = __builtin_elementwise_fma(wB2[2 * i + 1], h23, aB);
        }
        float gA = aA.x + aA.y;   // low: r-arg, high: z-arg (x log2e)
        float gB = aB.x + aB.y;   // n-dot + bias (x 2log2e)
        float sg = __builtin_amdgcn_rcpf(1.f + exp2f(-gA));   // low: r, high: z
#if __has_builtin(__builtin_amdgcn_permlane32_swap)
        uvec2 sw = __builtin_amdgcn_permlane32_swap(__float_as_uint(sg), __float_as_uint(sg), false, false);
        float zv = __uint_as_float(sw.y);    // low lanes: z from high half
#else
        float zv = __shfl_xor(sg, 32);
#endif
        float pre = fmaf(sg, gB, xnv);
        float t = exp2f(pre);
        float nn = fmaf(-2.f, __builtin_amdgcn_rcpf(t + 1.f), 1.f);  // tanh
        hloc = fmaf(zv, hloc - nn, nn);      // high lanes: bounded junk, never read
        if (j < 32) hb[ln * 36 + jl] = hloc;
        const float4* hrow = (const float4*)(hb + ln * 36);
#pragma unroll
        for (int i = 0; i < 8; i++) hv4[i] = hrow[i];
        xga = nxga; xnv = nxnv;
      }
    } else {
      int t64 = tid - 64;
      if (c + 1 < 16) {
        const float4* s4 = (const float4*)(xpb + (size_t)(c + 1) * CHUNK * 96);
        float4* d4 = (float4*)xbuf[(c + 1) & 1];
        for (int i = t64; i < CHUNK * 24; i += 192) d4[i] = s4[i];
      }
      if (c > 0) {
        const float* hb = hbuf[(c - 1) & 1];
        int n0b = (c - 1) * CHUNK;
#pragma unroll
        for (int qq = 0; qq < 4; qq++) {
          int idx = qq * 192 + t64;             // < 768 = 64 nodes x 12 outs
          int nl = idx / 12, o = idx - nl * 12;
          const float4* h4 = (const float4*)(hb + nl * 36);
          const float4* w4 = (const float4*)(wdec_s + o * 36);
          float acc = bdec_s[o];
#pragma unroll
          for (int i = 0; i < 8; i++) {
            float4 hv = h4[i], wv = w4[i];
            acc += fmaxf(hv.x, 0.f) * wv.x + fmaxf(hv.y, 0.f) * wv.y +
                   fmaxf(hv.z, 0.f) * wv.z + fmaxf(hv.w, 0.f) * wv.w;
          }
          out[(size_t)(b * N_ + n0b + nl) * 12 + o] = acc;
        }
      }
    }
    __syncthreads();
  }
  // decode last chunk
  {
    const float* hb = hbuf[1];   // chunk 15
    int n0b = 15 * CHUNK;
#pragma unroll
    for (int qq = 0; qq < 3; qq++) {
      int idx = qq * 256 + tid;
      int nl = idx / 12, o = idx - nl * 12;
      const float4* h4 = (const float4*)(hb + nl * 36);
      const float4* w4 = (const float4*)(wdec_s + o * 36);
      float acc = bdec_s[o];
#pragma unroll
      for (int i = 0; i < 8; i++) {
        float4 hv = h4[i], wv = w4[i];
        acc += fmaxf(hv.x, 0.f) * wv.x + fmaxf(hv.y, 0.f) * wv.y +
               fmaxf(hv.z, 0.f) * wv.z + fmaxf(hv.w, 0.f) * wv.w;
      }
      out[(size_t)(b * N_ + n0b + nl) * 12 + o] = acc;
    }
  }
}

extern "C" void kernel_launch(void* const* d_in, const int* in_sizes, int n_in,
                              void* d_out, int out_size, void* d_ws, size_t ws_size,
                              hipStream_t stream) {
  const float* x    = (const float*)d_in[0];
  const int*   ei   = (const int*)d_in[2];
  const float* ewt  = (const float*)d_in[3];
  const float* Wq   = (const float*)d_in[4];
  const float* bq   = (const float*)d_in[5];
  const float* Wk   = (const float*)d_in[6];
  const float* bk   = (const float*)d_in[7];
  const float* Wd   = (const float*)d_in[8];
  const float* bd   = (const float*)d_in[9];
  const float* c1w0 = (const float*)d_in[10];
  const float* c1b0 = (const float*)d_in[11];
  const float* c2w0 = (const float*)d_in[12];
  const float* c2b0 = (const float*)d_in[13];
  const float* dw0  = (const float*)d_in[14];
  const float* db0  = (const float*)d_in[15];
  const float* c1w1 = (const float*)d_in[16];
  const float* c1b1 = (const float*)d_in[17];
  const float* c2w1 = (const float*)d_in[18];
  const float* c2b1 = (const float*)d_in[19];
  const float* We   = (const float*)d_in[20];
  const float* be   = (const float*)d_in[21];
  const float* Wih  = (const float*)d_in[22];
  const float* Whh  = (const float*)d_in[23];
  const float* bih  = (const float*)d_in[24];
  const float* bhh  = (const float*)d_in[25];
  const float* Wdec = (const float*)d_in[26];
  const float* bdec = (const float*)d_in[27];
  float* out = (float*)d_out;
  float* w = (float*)d_ws;
  const int E = in_sizes[2] / 2;

  float* q2    = w + OFF_Q2;
  float* k1    = w + OFF_K1;
  float* k2    = w + OFF_K2;
  float* zinv2 = w + OFF_ZI;
  float* deg   = w + OFF_DEG;
  float* t1o   = w + OFF_Q2;   // reuse after edge_stats
  float* t1i   = w + OFF_K1;   // reuse after lse
  float* temp  = w + OFF_TEMP;
  float* WfT   = w + OFF_WFT;
  float* bf    = w + OFF_BF;
  float* xp    = w + OFF_XP;
  float* xT    = w + OFF_XT;
  int* ib   = (int*)(w + OFF_INT);
  int* rp   = ib;            // 1025
  int* cp   = ib + 1028;     // 1025
  int* eids = ib + 2056;     // E

  qk_prep_kernel<<<385, 1024, 0, stream>>>(x, Wq, bq, Wk, bk, q2, k1, k2, xT,
                                           ei, E, deg, rp, cp, eids,
                                           We, be, Wih, bih, WfT, bf);
  lse_tcn_kernel<<<512, 512, 0, stream>>>(q2, k1, zinv2, x,
                                          c1w0, c1b0, c2w0, c2b0, dw0, db0,
                                          c1w1, c1b1, c2w1, c2b1, temp);
  edge_stats_kernel<<<(E * 32 + 255) / 256, 256, 0, stream>>>(q2, k2, zinv2, ei, ewt, E, deg);
  gather_io_kernel<<<2 * N_, 384, 0, stream>>>(xT, ei, E, rp, cp, eids, deg, t1i, t1o);
  spatxp_kernel<<<B_ * 32, 384, 0, stream>>>(x, t1o, t1i, Wd, bd, temp, WfT, bf, xp);
  gru_kernel<<<B_, 256, 0, stream>>>(xp, Whh, bhh, Wdec, bdec, out);
}